// Round 5
// baseline (2429.952 us; speedup 1.0000x reference)
//
#include <hip/hip_runtime.h>
#include <math.h>

#define NFACT 50000
#define NST   2000
#define DFACT 768
#define HC    256
#define EM    500000
#define NK    10
#define NEG   0.2f
#define NCHUNK 196        // 196*256 = 50176 >= 50001
#define FBLK   1024       // 4 blocks/CU * 256 CUs -> guaranteed co-resident with __launch_bounds__(256,4)
#define FTHR   256

__device__ __forceinline__ float lrelu(float x) { return x > 0.f ? x : NEG * x; }

// Manual grid barrier: monotonic counter, device(agent)-scope atomics.
// ACQ_REL add publishes prior writes (L2 writeback); ACQUIRE spin-load invalidates
// reader caches. Spin cap turns any deadlock into a clean wrong-answer, not a hang.
__device__ __forceinline__ void gridbar(int* bar, int target) {
    __syncthreads();
    if (threadIdx.x == 0) {
        __hip_atomic_fetch_add(bar, 1, __ATOMIC_ACQ_REL, __HIP_MEMORY_SCOPE_AGENT);
        int guard = 0;
        while (__hip_atomic_load(bar, __ATOMIC_ACQUIRE, __HIP_MEMORY_SCOPE_AGENT) < target) {
            __builtin_amdgcn_s_sleep(2);
            if (++guard > (1 << 27)) break;   // ~fail-safe, never expected
        }
    }
    __syncthreads();
}

// ---- K1: whole front-end, one normal launch, manual grid barriers.
// A: V + zero counts | B: statute prep | cst | hist | ald(x_fact@V, overlaps hist)
// C: chunk sums | D: scan -> offs,cursor | E: CSR scatter
__global__ __launch_bounds__(256, 4) void k_front(const float* __restrict__ xs,
                                                  const float* __restrict__ xf,
                                                  const float* __restrict__ Wsrc,
                                                  const float* __restrict__ asrc,
                                                  const float* __restrict__ Wc,
                                                  const float* __restrict__ Wdst,
                                                  const float* __restrict__ adst,
                                                  const float* __restrict__ b_rm,
                                                  const float* __restrict__ bc,
                                                  const int* __restrict__ src,
                                                  const int* __restrict__ dst,
                                                  float* __restrict__ als,
                                                  float* __restrict__ hsW,
                                                  float* __restrict__ V,
                                                  float* __restrict__ cst,
                                                  float* __restrict__ ald,
                                                  int* __restrict__ counts,
                                                  int* __restrict__ bsum,
                                                  int* __restrict__ offs,
                                                  int* __restrict__ cursor,
                                                  int* __restrict__ perm_s,
                                                  int* __restrict__ bar) {
    __shared__ float xrow[256];
    __shared__ float hrow[256];
    __shared__ float wsum[4];
    __shared__ int   sq[4];
    __shared__ int   sbi[256];
    __shared__ int   sdi[256];

    int b = blockIdx.x, t = threadIdx.x;

    // ---- phase A: V (blocks 0..5) | zero counts (blocks 6..)
    if (b < 6) {
        int i = b * 256 + t;
        if (i < DFACT * 2) {
            int d = i >> 1, h = i & 1;
            float acc = 0.f;
            for (int c = 0; c < 128; ++c)
                acc += Wdst[d * 256 + h * 128 + c] * adst[h * 128 + c];
            V[d * 2 + h] = acc;
        }
    } else {
        int i = (b - 6) * 256 + t;
        if (i <= NFACT) counts[i] = 0;
    }
    gridbar(bar, FBLK);

    // ---- phase B: statute prep (b<200, 10 rows each) | cst (b==200) |
    //               hist (256<=b<320) | ald (320<=b<1024)
    if (b < 200) {
        for (int rr = 0; rr < 10; ++rr) {
            int s = b * 10 + rr;
            xrow[t] = xs[s * 256 + t];
            __syncthreads();
            float acc = 0.f;
            for (int d = 0; d < 256; ++d) acc += xrow[d] * Wsrc[d * 256 + t];
            float p = acc * asrc[t];             // t = h*128+c matches asrc [2][128]
            for (int o = 32; o; o >>= 1) p += __shfl_xor(p, o, 64);
            hrow[t] = acc;
            if ((t & 63) == 0) wsum[t >> 6] = p;
            __syncthreads();
            if (t < 20) {                        // t<10: head0,k=t ; else head1,k=t-10
                int h = t / 10, k = t - h * 10;
                float a = 0.f;
                int base = h * 128;
                for (int c = 0; c < 128; ++c) a += hrow[base + c] * Wc[(base + c) * NK + k];
                hsW[s * 20 + t] = a;
            }
            if (t == 0) { als[s * 2 + 0] = wsum[0] + wsum[1]; als[s * 2 + 1] = wsum[2] + wsum[3]; }
            __syncthreads();                     // LDS reused next row
        }
    } else if (b == 200) {
        if (t < NK) {
            float a = bc[t];
            for (int ch = 0; ch < HC; ++ch) a += b_rm[ch] * Wc[ch * NK + t];
            cst[t] = a;
        }
    } else if (b >= 256 && b < 320) {
        for (int e = (b - 256) * FTHR + t; e < EM; e += 64 * FTHR)
            atomicAdd(&counts[dst[e]], 1);
    } else if (b >= 320) {
        int lane = t & 63, wid = t >> 6;
        int w = (b - 320) * 4 + wid;             // 0..2815
        for (int n = w; n < NFACT; n += 2816) {
            const float* row = xf + (size_t)n * DFACT;
            float a0 = 0.f, a1 = 0.f;
            #pragma unroll
            for (int r = 0; r < 3; ++r) {
                int j0 = r * 256 + lane * 4;
                const float4 u = *(const float4*)(row + j0);
                a0 += u.x * V[(j0 + 0) * 2 + 0] + u.y * V[(j0 + 1) * 2 + 0]
                    + u.z * V[(j0 + 2) * 2 + 0] + u.w * V[(j0 + 3) * 2 + 0];
                a1 += u.x * V[(j0 + 0) * 2 + 1] + u.y * V[(j0 + 1) * 2 + 1]
                    + u.z * V[(j0 + 2) * 2 + 1] + u.w * V[(j0 + 3) * 2 + 1];
            }
            for (int o = 32; o; o >>= 1) { a0 += __shfl_xor(a0, o, 64); a1 += __shfl_xor(a1, o, 64); }
            if (lane == 0) { ald[n * 2 + 0] = a0; ald[n * 2 + 1] = a1; }
        }
    }
    gridbar(bar, 2 * FBLK);

    // ---- phase C: per-chunk sums
    if (b < NCHUNK) {
        int i = b * 256 + t;
        int c = (i <= NFACT) ? counts[i] : 0;
        int v = c;
        for (int o = 32; o; o >>= 1) v += __shfl_xor(v, o, 64);
        if ((t & 63) == 0) sq[t >> 6] = v;
        __syncthreads();
        if (t == 0) bsum[b] = sq[0] + sq[1] + sq[2] + sq[3];
    }
    gridbar(bar, 3 * FBLK);

    // ---- phase D: block-offset scan (redundant per block, 784 B) + intra-chunk scan
    if (b < NCHUNK) {
        sbi[t] = (t < NCHUNK) ? bsum[t] : 0;
        __syncthreads();
        for (int o = 1; o < 256; o <<= 1) {
            int v = (t >= o) ? sbi[t - o] : 0;
            __syncthreads();
            sbi[t] += v;
            __syncthreads();
        }
        int myoff = (b > 0) ? sbi[b - 1] : 0;
        int i = b * 256 + t;
        int c = (i <= NFACT) ? counts[i] : 0;
        sdi[t] = c;
        __syncthreads();
        for (int o = 1; o < 256; o <<= 1) {
            int v = (t >= o) ? sdi[t - o] : 0;
            __syncthreads();
            sdi[t] += v;
            __syncthreads();
        }
        if (i <= NFACT) {
            int excl = myoff + sdi[t] - c;
            offs[i] = excl;
            cursor[i] = excl;
        }
    }
    gridbar(bar, 4 * FBLK);

    // ---- phase E: CSR scatter (all blocks)
    for (int e = b * FTHR + t; e < EM; e += FBLK * FTHR) {
        int d = dst[e];
        int pos = atomicAdd(&cursor[d], 1);
        perm_s[pos] = src[e];
    }
}

// ---- K2: one wave per fact row; lanes 0..19 hold (head,k); ald loaded from workspace;
//          weights recomputed from L1-resident als. (Round-0-verified body.)
__global__ __launch_bounds__(256) void k_agg(const float* __restrict__ hsW,
                                             const int* __restrict__ offs,
                                             const int* __restrict__ perm_s,
                                             const float2* __restrict__ als2,
                                             const float2* __restrict__ ald2,
                                             const float* __restrict__ cst,
                                             float* __restrict__ out) {
    int lane = threadIdx.x & 63, wid = threadIdx.x >> 6;
    int n = blockIdx.x * 4 + wid;
    int beg = offs[n], end = offs[n + 1];
    bool live = lane < 20;
    bool h0   = lane < 10;
    float2 aldn = ald2[n];
    float al = h0 ? aldn.x : aldn.y;

    float acc = 0.f, den = 0.f;
    int j = beg;
    for (; j + 4 <= end; j += 4) {
        int sA = perm_s[j + 0], sB = perm_s[j + 1], sC = perm_s[j + 2], sD = perm_s[j + 3];
        float2 aA = als2[sA], aB = als2[sB], aC = als2[sC], aD = als2[sD];
        float hA = live ? hsW[sA * 20 + lane] : 0.f;
        float hB = live ? hsW[sB * 20 + lane] : 0.f;
        float hC = live ? hsW[sC * 20 + lane] : 0.f;
        float hD = live ? hsW[sD * 20 + lane] : 0.f;
        float wA = __expf(lrelu((h0 ? aA.x : aA.y) + al));
        float wB = __expf(lrelu((h0 ? aB.x : aB.y) + al));
        float wC = __expf(lrelu((h0 ? aC.x : aC.y) + al));
        float wD = __expf(lrelu((h0 ? aD.x : aD.y) + al));
        den += (wA + wB) + (wC + wD);
        acc += wA * hA + wB * hB + wC * hC + wD * hD;
    }
    for (; j < end; ++j) {
        int s = perm_s[j];
        float2 a = als2[s];
        float h = live ? hsW[s * 20 + lane] : 0.f;
        float w = __expf(lrelu((h0 ? a.x : a.y) + al));
        den += w;
        acc += w * h;
    }
    float r = acc / (den + 1e-16f);
    float other = __shfl(r, (lane + 10) & 63, 64);   // lane<10 pulls head1 partner
    if (h0) out[n * NK + lane] = r + other + cst[lane];
}

__global__ void k_sentinel(float* __restrict__ out, int n, float val) {
    int i = blockIdx.x * 256 + threadIdx.x;
    if (i < n) out[i] = val;
}

extern "C" void kernel_launch(void* const* d_in, const int* in_sizes, int n_in,
                              void* d_out, int out_size, void* d_ws, size_t ws_size,
                              hipStream_t stream) {
    const float* x_fact    = (const float*)d_in[0];
    const float* x_statute = (const float*)d_in[1];
    const float* Wsrc_rm   = (const float*)d_in[8];
    const float* Wdst_rm   = (const float*)d_in[9];
    const float* asrc_rm   = (const float*)d_in[10];
    const float* adst_rm   = (const float*)d_in[11];
    const float* b_rm      = (const float*)d_in[12];
    const float* Wc        = (const float*)d_in[23];
    const float* bc        = (const float*)d_in[24];
    const int* rm_src      = (const int*)d_in[27];
    const int* rm_dst      = (const int*)d_in[28];
    float* out = (float*)d_out;

    char* w0p = (char*)d_ws;
    char* w = w0p;
    auto carve = [&](size_t bytes) -> void* {
        void* p = (void*)w;
        w += (bytes + 511) & ~(size_t)511;
        return p;
    };
    float* als    = (float*)carve((size_t)NST * 2 * 4);
    float* hsW    = (float*)carve((size_t)NST * 20 * 4);
    float* V      = (float*)carve((size_t)DFACT * 2 * 4);
    float* cst    = (float*)carve(64);
    float* ald    = (float*)carve((size_t)NFACT * 2 * 4);
    int*   counts = (int*)carve((size_t)(NFACT + 1) * 4);
    int*   offs   = (int*)carve((size_t)(NFACT + 1) * 4);
    int*   cursor = (int*)carve((size_t)(NFACT + 1) * 4);
    int*   bsum   = (int*)carve((size_t)NCHUNK * 4);
    int*   perm_s = (int*)carve((size_t)EM * 4);
    int*   bar    = (int*)carve(64);
    if ((size_t)(w - w0p) > ws_size) {
        k_sentinel<<<(out_size + 255) / 256, 256, 0, stream>>>(out, out_size, 2000.f);
        return;
    }

    // Barrier counter must start at 0 each iteration (workspace is poisoned).
    (void)hipMemsetAsync(bar, 0, 64, stream);

    // K1: entire front-end, one normal (capture-safe) launch with manual grid barriers.
    k_front<<<FBLK, FTHR, 0, stream>>>(x_statute, x_fact, Wsrc_rm, asrc_rm, Wc,
                                       Wdst_rm, adst_rm, b_rm, bc,
                                       rm_src, rm_dst,
                                       als, hsW, V, cst, ald,
                                       counts, bsum, offs, cursor, perm_s, bar);

    // K2: per-row softmax-weighted aggregation -> classifier output
    k_agg<<<NFACT / 4, 256, 0, stream>>>(hsW, offs, perm_s,
                                         (const float2*)als, (const float2*)ald, cst, out);
}

// Round 6
// 403.628 us; speedup vs baseline: 6.0203x; 6.0203x over previous
//
#include <hip/hip_runtime.h>
#include <math.h>

#define NFACT 50000
#define NST   2000
#define DFACT 768
#define HC    256
#define EM    500000
#define NK    10
#define NEG   0.2f
#define NCHUNK 196        // 196*256 = 50176 >= 50001
#define PB     1024       // K1 grid: 200 prep + 1 cst + 6 V + 817 hist
#define HIST_B0 207

typedef float vf4 __attribute__((ext_vector_type(4)));

__device__ __forceinline__ float lrelu(float x) { return x > 0.f ? x : NEG * x; }

// ---- K1: prep (10 statute rows/block) | cst | V | histogram — all independent,
//          counts pre-zeroed by hipMemsetAsync, so no ordering needed inside.
__global__ __launch_bounds__(256) void k_preph(const float* __restrict__ xs,
                                               const float* __restrict__ Wsrc,
                                               const float* __restrict__ asrc,
                                               const float* __restrict__ Wc,
                                               const float* __restrict__ Wdst,
                                               const float* __restrict__ adst,
                                               const float* __restrict__ b_rm,
                                               const float* __restrict__ bc,
                                               const int* __restrict__ dst,
                                               float* __restrict__ als,
                                               float* __restrict__ hsW,
                                               float* __restrict__ V,
                                               float* __restrict__ cst,
                                               int* __restrict__ counts) {
    int b = blockIdx.x, t = threadIdx.x;
    if (b < 200) {
        __shared__ float xrow[256];
        __shared__ float hrow[256];
        __shared__ float wsum[4];
        for (int rr = 0; rr < 10; ++rr) {
            int s = b * 10 + rr;
            xrow[t] = xs[s * 256 + t];
            __syncthreads();
            float acc = 0.f;
            for (int d = 0; d < 256; ++d) acc += xrow[d] * Wsrc[d * 256 + t];
            float p = acc * asrc[t];             // t = h*128+c matches asrc [2][128]
            for (int o = 32; o; o >>= 1) p += __shfl_xor(p, o, 64);
            hrow[t] = acc;
            if ((t & 63) == 0) wsum[t >> 6] = p;
            __syncthreads();
            if (t < 20) {                        // t<10: head0,k=t ; else head1,k=t-10
                int h = t / 10, k = t - h * 10;
                float a = 0.f;
                int base = h * 128;
                for (int c = 0; c < 128; ++c) a += hrow[base + c] * Wc[(base + c) * NK + k];
                hsW[s * 20 + t] = a;
            }
            if (t == 0) { als[s * 2 + 0] = wsum[0] + wsum[1]; als[s * 2 + 1] = wsum[2] + wsum[3]; }
            __syncthreads();                     // LDS reused next row
        }
    } else if (b == 200) {
        if (t < NK) {
            float a = bc[t];
            for (int ch = 0; ch < HC; ++ch) a += b_rm[ch] * Wc[ch * NK + t];
            cst[t] = a;
        }
    } else if (b < HIST_B0) {
        int i = (b - 201) * 256 + t;
        if (i < DFACT * 2) {
            int d = i >> 1, h = i & 1;
            float acc = 0.f;
            for (int c = 0; c < 128; ++c)
                acc += Wdst[d * 256 + h * 128 + c] * adst[h * 128 + c];
            V[d * 2 + h] = acc;
        }
    } else {
        const int stride = (PB - HIST_B0) * 256;
        for (int e = (b - HIST_B0) * 256 + t; e < EM; e += stride)
            atomicAdd(&counts[dst[e]], 1);
    }
}

// ---- K2: per-chunk sums (196 blocks)
__global__ __launch_bounds__(256) void k_scanA(const int* __restrict__ counts,
                                               int* __restrict__ bsum) {
    __shared__ int sd[4];
    int t = threadIdx.x, i = blockIdx.x * 256 + t;
    int c = (i <= NFACT) ? counts[i] : 0;
    int v = c;
    for (int o = 32; o; o >>= 1) v += __shfl_xor(v, o, 64);
    if ((t & 63) == 0) sd[t >> 6] = v;
    __syncthreads();
    if (t == 0) bsum[blockIdx.x] = sd[0] + sd[1] + sd[2] + sd[3];
}

// ---- K3: fused scanB+scanC (each block redundantly scans 196 chunk sums, 784 B)
__global__ __launch_bounds__(256) void k_scanBC(const int* __restrict__ counts,
                                                const int* __restrict__ bsum,
                                                int* __restrict__ offs,
                                                int* __restrict__ cursor) {
    __shared__ int sb[256];
    __shared__ int sd[256];
    int t = threadIdx.x, b = blockIdx.x;
    sb[t] = (t < NCHUNK) ? bsum[t] : 0;
    __syncthreads();
    for (int o = 1; o < 256; o <<= 1) {
        int v = (t >= o) ? sb[t - o] : 0;
        __syncthreads();
        sb[t] += v;
        __syncthreads();
    }
    int myoff = (b > 0) ? sb[b - 1] : 0;
    int i = b * 256 + t;
    int c = (i <= NFACT) ? counts[i] : 0;
    sd[t] = c;
    __syncthreads();
    for (int o = 1; o < 256; o <<= 1) {
        int v = (t >= o) ? sd[t - o] : 0;
        __syncthreads();
        sd[t] += v;
        __syncthreads();
    }
    if (i <= NFACT) {
        int excl = myoff + sd[t] - c;
        offs[i] = excl;
        cursor[i] = excl;
    }
}

// ---- K4: parallel CSR scatter, one edge per thread
__global__ void k_scat(const int* __restrict__ src, const int* __restrict__ dst,
                       int* __restrict__ cursor, int* __restrict__ perm_s) {
    int e = blockIdx.x * 256 + threadIdx.x;
    if (e >= EM) return;
    int d = dst[e];
    int pos = atomicAdd(&cursor[d], 1);
    perm_s[pos] = src[e];
}

// ---- K5: one wave per fact row. Phase 1: ald = x_fact[n] @ V (nontemporal stream).
//          Phase 2: edge loop; wid via readfirstlane so offs/perm_s/als become s_loads.
__global__ __launch_bounds__(256) void k_agg(const float* __restrict__ xf,
                                             const float* __restrict__ V,
                                             const float* __restrict__ hsW,
                                             const int* __restrict__ offs,
                                             const int* __restrict__ perm_s,
                                             const float2* __restrict__ als2,
                                             const float* __restrict__ cst,
                                             float* __restrict__ out) {
    int lane = threadIdx.x & 63;
    int wid = __builtin_amdgcn_readfirstlane(threadIdx.x >> 6);   // wave-uniform -> SGPR
    int n = blockIdx.x * 4 + wid;

    // ---- phase 1: ald for this row (x_fact streamed once -> nontemporal)
    const float* row = xf + (size_t)n * DFACT;
    float a0 = 0.f, a1 = 0.f;
    #pragma unroll
    for (int r = 0; r < 3; ++r) {
        int j0 = r * 256 + lane * 4;
        const vf4 u = __builtin_nontemporal_load((const vf4*)(row + j0));
        a0 += u.x * V[(j0 + 0) * 2 + 0] + u.y * V[(j0 + 1) * 2 + 0]
            + u.z * V[(j0 + 2) * 2 + 0] + u.w * V[(j0 + 3) * 2 + 0];
        a1 += u.x * V[(j0 + 0) * 2 + 1] + u.y * V[(j0 + 1) * 2 + 1]
            + u.z * V[(j0 + 2) * 2 + 1] + u.w * V[(j0 + 3) * 2 + 1];
    }
    for (int o = 32; o; o >>= 1) { a0 += __shfl_xor(a0, o, 64); a1 += __shfl_xor(a1, o, 64); }

    // ---- phase 2: softmax-weighted aggregation
    bool live = lane < 20;
    bool h0   = lane < 10;
    float al = h0 ? a0 : a1;
    int beg = offs[n], end = offs[n + 1];

    float acc = 0.f, den = 0.f;
    int j = beg;
    for (; j + 4 <= end; j += 4) {
        int sA = perm_s[j + 0], sB = perm_s[j + 1], sC = perm_s[j + 2], sD = perm_s[j + 3];
        float2 aA = als2[sA], aB = als2[sB], aC = als2[sC], aD = als2[sD];
        float hA = live ? hsW[sA * 20 + lane] : 0.f;
        float hB = live ? hsW[sB * 20 + lane] : 0.f;
        float hC = live ? hsW[sC * 20 + lane] : 0.f;
        float hD = live ? hsW[sD * 20 + lane] : 0.f;
        float wA = __expf(lrelu((h0 ? aA.x : aA.y) + al));
        float wB = __expf(lrelu((h0 ? aB.x : aB.y) + al));
        float wC = __expf(lrelu((h0 ? aC.x : aC.y) + al));
        float wD = __expf(lrelu((h0 ? aD.x : aD.y) + al));
        den += (wA + wB) + (wC + wD);
        acc += wA * hA + wB * hB + wC * hC + wD * hD;
    }
    for (; j < end; ++j) {
        int s = perm_s[j];
        float2 a = als2[s];
        float h = live ? hsW[s * 20 + lane] : 0.f;
        float w = __expf(lrelu((h0 ? a.x : a.y) + al));
        den += w;
        acc += w * h;
    }
    float r = acc / (den + 1e-16f);
    float other = __shfl(r, (lane + 10) & 63, 64);   // lane<10 pulls head1 partner
    if (h0) out[n * NK + lane] = r + other + cst[lane];
}

__global__ void k_sentinel(float* __restrict__ out, int n, float val) {
    int i = blockIdx.x * 256 + threadIdx.x;
    if (i < n) out[i] = val;
}

extern "C" void kernel_launch(void* const* d_in, const int* in_sizes, int n_in,
                              void* d_out, int out_size, void* d_ws, size_t ws_size,
                              hipStream_t stream) {
    const float* x_fact    = (const float*)d_in[0];
    const float* x_statute = (const float*)d_in[1];
    const float* Wsrc_rm   = (const float*)d_in[8];
    const float* Wdst_rm   = (const float*)d_in[9];
    const float* asrc_rm   = (const float*)d_in[10];
    const float* adst_rm   = (const float*)d_in[11];
    const float* b_rm      = (const float*)d_in[12];
    const float* Wc        = (const float*)d_in[23];
    const float* bc        = (const float*)d_in[24];
    const int* rm_src      = (const int*)d_in[27];
    const int* rm_dst      = (const int*)d_in[28];
    float* out = (float*)d_out;

    char* w0p = (char*)d_ws;
    char* w = w0p;
    auto carve = [&](size_t bytes) -> void* {
        void* p = (void*)w;
        w += (bytes + 511) & ~(size_t)511;
        return p;
    };
    float* als    = (float*)carve((size_t)NST * 2 * 4);
    float* hsW    = (float*)carve((size_t)NST * 20 * 4);
    float* V      = (float*)carve((size_t)DFACT * 2 * 4);
    float* cst    = (float*)carve(64);
    int*   counts = (int*)carve((size_t)(NFACT + 1) * 4);
    int*   offs   = (int*)carve((size_t)(NFACT + 1) * 4);
    int*   cursor = (int*)carve((size_t)(NFACT + 1) * 4);
    int*   bsum   = (int*)carve((size_t)NCHUNK * 4);
    int*   perm_s = (int*)carve((size_t)EM * 4);
    if ((size_t)(w - w0p) > ws_size) {
        k_sentinel<<<(out_size + 255) / 256, 256, 0, stream>>>(out, out_size, 2000.f);
        return;
    }

    // counts zeroed via async memset (capture-safe; verified round 5) -> prep+hist mergeable
    (void)hipMemsetAsync(counts, 0, (size_t)(NFACT + 1) * 4, stream);

    // K1: statute prep (10 rows/block) + cst + V + histogram, one launch
    k_preph<<<PB, 256, 0, stream>>>(x_statute, Wsrc_rm, asrc_rm, Wc,
                                    Wdst_rm, adst_rm, b_rm, bc, rm_dst,
                                    als, hsW, V, cst, counts);
    // K2: chunk sums
    k_scanA<<<NCHUNK, 256, 0, stream>>>(counts, bsum);
    // K3: fused block-offset + intra-chunk scan -> offs, cursor
    k_scanBC<<<NCHUNK, 256, 0, stream>>>(counts, bsum, offs, cursor);
    // K4: CSR scatter
    k_scat<<<(EM + 255) / 256, 256, 0, stream>>>(rm_src, rm_dst, cursor, perm_s);
    // K5: fused ald + softmax-weighted aggregation -> classifier output
    k_agg<<<NFACT / 4, 256, 0, stream>>>(x_fact, V, hsW, offs, perm_s,
                                         (const float2*)als, cst, out);
}

// Round 7
// 350.593 us; speedup vs baseline: 6.9310x; 1.1513x over previous
//
#include <hip/hip_runtime.h>
#include <math.h>

#define NFACT 50000
#define NST   2000
#define DFACT 768
#define HC    256
#define EM    500000
#define NK    10
#define NEG   0.2f
#define NCHUNK 196        // 196*256 = 50176 >= 50001
#define NB0    541        // K0: 1 cst + 6 V + 22 B-cols + 512 hist
#define K1_ALS  500       // 2000 statute rows, 4/block
#define K1_SCAN (K1_ALS + NCHUNK)          // 696
#define K1_TOT  (K1_SCAN + NFACT / 4)      // 13196

typedef float vf4 __attribute__((ext_vector_type(4)));

__device__ __forceinline__ float lrelu(float x) { return x > 0.f ? x : NEG * x; }

// ---- K0: cst | V | B = [W2 | A2] fold | histogram — all independent.
//  b==0      : cst[k] = b_rm @ Wc + bc
//  b in[1,7) : V[d,h] = sum_c Wdst[d,h*128+c] * adst[h,c]
//  b in[7,29): B[d][o] ; o<20: h=o/10,k=o%10: sum_c Wsrc[d,h*128+c]*Wc[h*128+c,k]
//                        o in{20,21}: h=o-20:  sum_c Wsrc[d,h*128+c]*asrc[h,c]
//  b>=29     : histogram of rm_dst into counts (pre-zeroed by memset)
__global__ __launch_bounds__(256) void k_pre(const float* __restrict__ Wsrc,
                                             const float* __restrict__ asrc,
                                             const float* __restrict__ Wc,
                                             const float* __restrict__ Wdst,
                                             const float* __restrict__ adst,
                                             const float* __restrict__ b_rm,
                                             const float* __restrict__ bc,
                                             const int* __restrict__ dst,
                                             float* __restrict__ V,
                                             float* __restrict__ B,
                                             float* __restrict__ cst,
                                             int* __restrict__ counts) {
    int b = blockIdx.x, t = threadIdx.x;
    if (b == 0) {
        if (t < NK) {
            float a = bc[t];
            for (int ch = 0; ch < HC; ++ch) a += b_rm[ch] * Wc[ch * NK + t];
            cst[t] = a;
        }
    } else if (b < 7) {
        int i = (b - 1) * 256 + t;
        if (i < DFACT * 2) {
            int d = i >> 1, h = i & 1;
            float acc = 0.f;
            for (int c = 0; c < 128; ++c)
                acc += Wdst[d * 256 + h * 128 + c] * adst[h * 128 + c];
            V[d * 2 + h] = acc;
        }
    } else if (b < 29) {
        int o = b - 7, d = t;
        float acc = 0.f;
        if (o < 20) {
            int h = o / 10, k = o - (o / 10) * 10;
            const float* wr = Wsrc + d * 256 + h * 128;
            const float* wc = Wc + (h * 128) * NK + k;
            for (int c = 0; c < 128; ++c) acc += wr[c] * wc[c * NK];
        } else {
            int h = o - 20;
            const float* wr = Wsrc + d * 256 + h * 128;
            const float* ar = asrc + h * 128;
            for (int c = 0; c < 128; ++c) acc += wr[c] * ar[c];
        }
        B[d * 22 + o] = acc;
    } else {
        const int stride = (NB0 - 29) * 256;
        for (int e = (b - 29) * 256 + t; e < EM; e += stride)
            atomicAdd(&counts[dst[e]], 1);
    }
}

// ---- K1: als+hsW rows | scanA chunk sums | ald rows. One wave per row (skinny GEMM).
//  b < 500        : statute row s = b*4+wid: [hsW[s,0..19], als[s,0..1]] = xs[s,:] @ B
//  500 <= b < 696 : per-chunk count sums -> bsum
//  b >= 696       : fact row n: ald[n,h] = xf[n,:] @ V  (nontemporal 153.6 MB stream)
__global__ __launch_bounds__(256) void k_rows(const float* __restrict__ xs,
                                              const float* __restrict__ xf,
                                              const float* __restrict__ B,
                                              const float* __restrict__ V,
                                              const int* __restrict__ counts,
                                              float* __restrict__ als,
                                              float* __restrict__ hsW,
                                              float* __restrict__ ald,
                                              int* __restrict__ bsum) {
    int b = blockIdx.x, t = threadIdx.x;
    int lane = t & 63, wid = t >> 6;
    if (b < K1_ALS) {
        int s = b * 4 + wid;
        const vf4 u = *(const vf4*)(xs + s * 256 + lane * 4);
        float acc[22];
        #pragma unroll
        for (int o = 0; o < 22; ++o) acc[o] = 0.f;
        const float* Bd = B + (lane * 4) * 22;
        #pragma unroll
        for (int i = 0; i < 4; ++i) {
            float x = (i == 0) ? u.x : (i == 1) ? u.y : (i == 2) ? u.z : u.w;
            #pragma unroll
            for (int o = 0; o < 22; ++o) acc[o] += x * Bd[i * 22 + o];
        }
        #pragma unroll
        for (int o = 0; o < 22; ++o) {
            #pragma unroll
            for (int off = 32; off; off >>= 1) acc[o] += __shfl_xor(acc[o], off, 64);
        }
        if (lane == 0) {
            #pragma unroll
            for (int o = 0; o < 20; ++o) hsW[s * 20 + o] = acc[o];
            als[s * 2 + 0] = acc[20];
            als[s * 2 + 1] = acc[21];
        }
    } else if (b < K1_SCAN) {
        __shared__ int sd[4];
        int i = (b - K1_ALS) * 256 + t;
        int c = (i <= NFACT) ? counts[i] : 0;
        int v = c;
        for (int o = 32; o; o >>= 1) v += __shfl_xor(v, o, 64);
        if ((t & 63) == 0) sd[t >> 6] = v;
        __syncthreads();
        if (t == 0) bsum[b - K1_ALS] = sd[0] + sd[1] + sd[2] + sd[3];
    } else {
        int n = (b - K1_SCAN) * 4 + wid;
        const float* row = xf + (size_t)n * DFACT;
        float a0 = 0.f, a1 = 0.f;
        #pragma unroll
        for (int r = 0; r < 3; ++r) {
            int j0 = r * 256 + lane * 4;
            const vf4 u = __builtin_nontemporal_load((const vf4*)(row + j0));
            a0 += u.x * V[(j0 + 0) * 2 + 0] + u.y * V[(j0 + 1) * 2 + 0]
                + u.z * V[(j0 + 2) * 2 + 0] + u.w * V[(j0 + 3) * 2 + 0];
            a1 += u.x * V[(j0 + 0) * 2 + 1] + u.y * V[(j0 + 1) * 2 + 1]
                + u.z * V[(j0 + 2) * 2 + 1] + u.w * V[(j0 + 3) * 2 + 1];
        }
        for (int o = 32; o; o >>= 1) { a0 += __shfl_xor(a0, o, 64); a1 += __shfl_xor(a1, o, 64); }
        if (lane == 0) { ald[n * 2 + 0] = a0; ald[n * 2 + 1] = a1; }
    }
}

// ---- K2: fused scanB+scanC (each block redundantly scans 196 chunk sums, 784 B)
__global__ __launch_bounds__(256) void k_scanBC(const int* __restrict__ counts,
                                                const int* __restrict__ bsum,
                                                int* __restrict__ offs,
                                                int* __restrict__ cursor) {
    __shared__ int sb[256];
    __shared__ int sd[256];
    int t = threadIdx.x, b = blockIdx.x;
    sb[t] = (t < NCHUNK) ? bsum[t] : 0;
    __syncthreads();
    for (int o = 1; o < 256; o <<= 1) {
        int v = (t >= o) ? sb[t - o] : 0;
        __syncthreads();
        sb[t] += v;
        __syncthreads();
    }
    int myoff = (b > 0) ? sb[b - 1] : 0;
    int i = b * 256 + t;
    int c = (i <= NFACT) ? counts[i] : 0;
    sd[t] = c;
    __syncthreads();
    for (int o = 1; o < 256; o <<= 1) {
        int v = (t >= o) ? sd[t - o] : 0;
        __syncthreads();
        sd[t] += v;
        __syncthreads();
    }
    if (i <= NFACT) {
        int excl = myoff + sd[t] - c;
        offs[i] = excl;
        cursor[i] = excl;
    }
}

// ---- K3: parallel CSR scatter, one edge per thread
__global__ void k_scat(const int* __restrict__ src, const int* __restrict__ dst,
                       int* __restrict__ cursor, int* __restrict__ perm_s) {
    int e = blockIdx.x * 256 + threadIdx.x;
    if (e >= EM) return;
    int d = dst[e];
    int pos = atomicAdd(&cursor[d], 1);
    perm_s[pos] = src[e];
}

// ---- K4: one wave per fact row; lanes 0..19 hold (head,k); ald loaded; weights
//          recomputed from L1-resident als. (Round-5-verified body.)
__global__ __launch_bounds__(256) void k_agg(const float* __restrict__ hsW,
                                             const int* __restrict__ offs,
                                             const int* __restrict__ perm_s,
                                             const float2* __restrict__ als2,
                                             const float2* __restrict__ ald2,
                                             const float* __restrict__ cst,
                                             float* __restrict__ out) {
    int lane = threadIdx.x & 63;
    int wid = __builtin_amdgcn_readfirstlane(threadIdx.x >> 6);
    int n = blockIdx.x * 4 + wid;
    int beg = offs[n], end = offs[n + 1];
    bool live = lane < 20;
    bool h0   = lane < 10;
    float2 aldn = ald2[n];
    float al = h0 ? aldn.x : aldn.y;

    float acc = 0.f, den = 0.f;
    int j = beg;
    for (; j + 4 <= end; j += 4) {
        int sA = perm_s[j + 0], sB = perm_s[j + 1], sC = perm_s[j + 2], sD = perm_s[j + 3];
        float2 aA = als2[sA], aB = als2[sB], aC = als2[sC], aD = als2[sD];
        float hA = live ? hsW[sA * 20 + lane] : 0.f;
        float hB = live ? hsW[sB * 20 + lane] : 0.f;
        float hC = live ? hsW[sC * 20 + lane] : 0.f;
        float hD = live ? hsW[sD * 20 + lane] : 0.f;
        float wA = __expf(lrelu((h0 ? aA.x : aA.y) + al));
        float wB = __expf(lrelu((h0 ? aB.x : aB.y) + al));
        float wC = __expf(lrelu((h0 ? aC.x : aC.y) + al));
        float wD = __expf(lrelu((h0 ? aD.x : aD.y) + al));
        den += (wA + wB) + (wC + wD);
        acc += wA * hA + wB * hB + wC * hC + wD * hD;
    }
    for (; j < end; ++j) {
        int s = perm_s[j];
        float2 a = als2[s];
        float h = live ? hsW[s * 20 + lane] : 0.f;
        float w = __expf(lrelu((h0 ? a.x : a.y) + al));
        den += w;
        acc += w * h;
    }
    float r = acc / (den + 1e-16f);
    float other = __shfl(r, (lane + 10) & 63, 64);   // lane<10 pulls head1 partner
    if (h0) out[n * NK + lane] = r + other + cst[lane];
}

__global__ void k_sentinel(float* __restrict__ out, int n, float val) {
    int i = blockIdx.x * 256 + threadIdx.x;
    if (i < n) out[i] = val;
}

extern "C" void kernel_launch(void* const* d_in, const int* in_sizes, int n_in,
                              void* d_out, int out_size, void* d_ws, size_t ws_size,
                              hipStream_t stream) {
    const float* x_fact    = (const float*)d_in[0];
    const float* x_statute = (const float*)d_in[1];
    const float* Wsrc_rm   = (const float*)d_in[8];
    const float* Wdst_rm   = (const float*)d_in[9];
    const float* asrc_rm   = (const float*)d_in[10];
    const float* adst_rm   = (const float*)d_in[11];
    const float* b_rm      = (const float*)d_in[12];
    const float* Wc        = (const float*)d_in[23];
    const float* bc        = (const float*)d_in[24];
    const int* rm_src      = (const int*)d_in[27];
    const int* rm_dst      = (const int*)d_in[28];
    float* out = (float*)d_out;

    char* w0p = (char*)d_ws;
    char* w = w0p;
    auto carve = [&](size_t bytes) -> void* {
        void* p = (void*)w;
        w += (bytes + 511) & ~(size_t)511;
        return p;
    };
    float* als    = (float*)carve((size_t)NST * 2 * 4);
    float* hsW    = (float*)carve((size_t)NST * 20 * 4);
    float* V      = (float*)carve((size_t)DFACT * 2 * 4);
    float* B      = (float*)carve((size_t)256 * 22 * 4);
    float* cst    = (float*)carve(64);
    float* ald    = (float*)carve((size_t)NFACT * 2 * 4);
    int*   counts = (int*)carve((size_t)(NFACT + 1) * 4);
    int*   offs   = (int*)carve((size_t)(NFACT + 1) * 4);
    int*   cursor = (int*)carve((size_t)(NFACT + 1) * 4);
    int*   bsum   = (int*)carve((size_t)NCHUNK * 4);
    int*   perm_s = (int*)carve((size_t)EM * 4);
    if ((size_t)(w - w0p) > ws_size) {
        k_sentinel<<<(out_size + 255) / 256, 256, 0, stream>>>(out, out_size, 2000.f);
        return;
    }

    // counts zeroed via async memset (capture-safe, verified) -> hist can ride in K0
    (void)hipMemsetAsync(counts, 0, (size_t)(NFACT + 1) * 4, stream);

    // K0: cst + V + B-fold + histogram
    k_pre<<<NB0, 256, 0, stream>>>(Wsrc_rm, asrc_rm, Wc, Wdst_rm, adst_rm,
                                   b_rm, bc, rm_dst, V, B, cst, counts);
    // K1: statute rows (als+hsW) | chunk sums | fact rows (ald)
    k_rows<<<K1_TOT, 256, 0, stream>>>(x_statute, x_fact, B, V, counts,
                                       als, hsW, ald, bsum);
    // K2: fused block-offset + intra-chunk scan -> offs, cursor
    k_scanBC<<<NCHUNK, 256, 0, stream>>>(counts, bsum, offs, cursor);
    // K3: CSR scatter
    k_scat<<<(EM + 255) / 256, 256, 0, stream>>>(rm_src, rm_dst, cursor, perm_s);
    // K4: per-row softmax-weighted aggregation -> classifier output
    k_agg<<<NFACT / 4, 256, 0, stream>>>(hsW, offs, perm_s,
                                         (const float2*)als, (const float2*)ald, cst, out);
}

// Round 8
// 340.065 us; speedup vs baseline: 7.1455x; 1.0310x over previous
//
#include <hip/hip_runtime.h>
#include <math.h>

#define NFACT 50000
#define NST   2000
#define DFACT 768
#define HC    256
#define EM    500000
#define NK    10
#define NEG   0.2f
#define MAXDEG 64         // Poisson(10): P(deg>=64) < 1e-35 — clamped defensively
#define PRE_SCAT0 2007    // k_pre: 1 cst + 6 V + 2000 statute rows, then scatter blocks

typedef float vf4 __attribute__((ext_vector_type(4)));

__device__ __forceinline__ float lrelu(float x) { return x > 0.f ? x : NEG * x; }

// ---- K0: cst | V | statute hs->als,hsW (1 row/block, round-0-verified body) |
//          atomic-slot scatter (needs only zeroed cursor). All parts independent.
__global__ __launch_bounds__(256) void k_pre(const float* __restrict__ xs,
                                             const float* __restrict__ Wsrc,
                                             const float* __restrict__ asrc,
                                             const float* __restrict__ Wc,
                                             const float* __restrict__ Wdst,
                                             const float* __restrict__ adst,
                                             const float* __restrict__ b_rm,
                                             const float* __restrict__ bc,
                                             const int* __restrict__ src,
                                             const int* __restrict__ dst,
                                             float* __restrict__ als,
                                             float* __restrict__ hsW,
                                             float* __restrict__ V,
                                             float* __restrict__ cst,
                                             int* __restrict__ cursor,
                                             int* __restrict__ perm) {
    int b = blockIdx.x, t = threadIdx.x;
    if (b == 0) {
        if (t < NK) {
            float a = bc[t];
            for (int ch = 0; ch < HC; ++ch) a += b_rm[ch] * Wc[ch * NK + t];
            cst[t] = a;
        }
    } else if (b < 7) {
        int i = (b - 1) * 256 + t;
        if (i < DFACT * 2) {
            int d = i >> 1, h = i & 1;
            float acc = 0.f;
            for (int c = 0; c < 128; ++c)
                acc += Wdst[d * 256 + h * 128 + c] * adst[h * 128 + c];
            V[d * 2 + h] = acc;
        }
    } else if (b < PRE_SCAT0) {
        int s = b - 7;
        __shared__ float xrow[256];
        __shared__ float hrow[256];
        __shared__ float wsum[4];
        xrow[t] = xs[s * 256 + t];
        __syncthreads();
        float acc = 0.f;
        for (int d = 0; d < 256; ++d) acc += xrow[d] * Wsrc[d * 256 + t];
        float p = acc * asrc[t];                 // t = h*128+c matches asrc [2][128]
        for (int o = 32; o; o >>= 1) p += __shfl_xor(p, o, 64);
        hrow[t] = acc;
        if ((t & 63) == 0) wsum[t >> 6] = p;
        __syncthreads();
        if (t < 20) {                            // t<10: head0,k=t ; else head1,k=t-10
            int h = t / 10, k = t - h * 10;
            float a = 0.f;
            int base = h * 128;
            for (int c = 0; c < 128; ++c) a += hrow[base + c] * Wc[(base + c) * NK + k];
            hsW[s * 20 + t] = a;
        }
        if (t == 0) { als[s * 2 + 0] = wsum[0] + wsum[1]; als[s * 2 + 1] = wsum[2] + wsum[3]; }
    } else {
        int e = (b - PRE_SCAT0) * 256 + t;
        if (e < EM) {
            int d = dst[e];
            int pos = atomicAdd(&cursor[d], 1);
            if (pos < MAXDEG) perm[(size_t)d * MAXDEG + pos] = src[e];
        }
    }
}

// ---- K1: one wave per fact row. Phase 1: ald = x_fact[n] @ V (nontemporal stream,
//          butterfly reduce -> both sums in all lanes). Phase 2: edge loop over the
//          row's atomic-slot bucket; lanes 0..19 hold (head,k); weights recomputed
//          from L1-resident als. (Round-2-verified fused body.)
__global__ __launch_bounds__(256) void k_agg(const float* __restrict__ xf,
                                             const float* __restrict__ V,
                                             const float* __restrict__ hsW,
                                             const int* __restrict__ cursor,
                                             const int* __restrict__ perm,
                                             const float2* __restrict__ als2,
                                             const float* __restrict__ cst,
                                             float* __restrict__ out) {
    int lane = threadIdx.x & 63;
    int wid = __builtin_amdgcn_readfirstlane(threadIdx.x >> 6);
    int n = blockIdx.x * 4 + wid;

    // ---- phase 1: ald for this row
    const float* row = xf + (size_t)n * DFACT;
    float a0 = 0.f, a1 = 0.f;
    #pragma unroll
    for (int r = 0; r < 3; ++r) {
        int j0 = r * 256 + lane * 4;
        const vf4 u = __builtin_nontemporal_load((const vf4*)(row + j0));
        a0 += u.x * V[(j0 + 0) * 2 + 0] + u.y * V[(j0 + 1) * 2 + 0]
            + u.z * V[(j0 + 2) * 2 + 0] + u.w * V[(j0 + 3) * 2 + 0];
        a1 += u.x * V[(j0 + 0) * 2 + 1] + u.y * V[(j0 + 1) * 2 + 1]
            + u.z * V[(j0 + 2) * 2 + 1] + u.w * V[(j0 + 3) * 2 + 1];
    }
    for (int o = 32; o; o >>= 1) { a0 += __shfl_xor(a0, o, 64); a1 += __shfl_xor(a1, o, 64); }

    // ---- phase 2: softmax-weighted aggregation over bucket
    bool live = lane < 20;
    bool h0   = lane < 10;
    float al = h0 ? a0 : a1;
    int cnt = cursor[n];
    cnt = (cnt > MAXDEG) ? MAXDEG : cnt;
    const int* pp = perm + (size_t)n * MAXDEG;

    float acc = 0.f, den = 0.f;
    int j = 0;
    for (; j + 4 <= cnt; j += 4) {
        int sA = pp[j + 0], sB = pp[j + 1], sC = pp[j + 2], sD = pp[j + 3];
        float2 aA = als2[sA], aB = als2[sB], aC = als2[sC], aD = als2[sD];
        float hA = live ? hsW[sA * 20 + lane] : 0.f;
        float hB = live ? hsW[sB * 20 + lane] : 0.f;
        float hC = live ? hsW[sC * 20 + lane] : 0.f;
        float hD = live ? hsW[sD * 20 + lane] : 0.f;
        float wA = __expf(lrelu((h0 ? aA.x : aA.y) + al));
        float wB = __expf(lrelu((h0 ? aB.x : aB.y) + al));
        float wC = __expf(lrelu((h0 ? aC.x : aC.y) + al));
        float wD = __expf(lrelu((h0 ? aD.x : aD.y) + al));
        den += (wA + wB) + (wC + wD);
        acc += wA * hA + wB * hB + wC * hC + wD * hD;
    }
    for (; j < cnt; ++j) {
        int s = pp[j];
        float2 a = als2[s];
        float h = live ? hsW[s * 20 + lane] : 0.f;
        float w = __expf(lrelu((h0 ? a.x : a.y) + al));
        den += w;
        acc += w * h;
    }
    float r = acc / (den + 1e-16f);
    float other = __shfl(r, (lane + 10) & 63, 64);   // lane<10 pulls head1 partner
    if (h0) out[n * NK + lane] = r + other + cst[lane];
}

__global__ void k_sentinel(float* __restrict__ out, int n, float val) {
    int i = blockIdx.x * 256 + threadIdx.x;
    if (i < n) out[i] = val;
}

extern "C" void kernel_launch(void* const* d_in, const int* in_sizes, int n_in,
                              void* d_out, int out_size, void* d_ws, size_t ws_size,
                              hipStream_t stream) {
    const float* x_fact    = (const float*)d_in[0];
    const float* x_statute = (const float*)d_in[1];
    const float* Wsrc_rm   = (const float*)d_in[8];
    const float* Wdst_rm   = (const float*)d_in[9];
    const float* asrc_rm   = (const float*)d_in[10];
    const float* adst_rm   = (const float*)d_in[11];
    const float* b_rm      = (const float*)d_in[12];
    const float* Wc        = (const float*)d_in[23];
    const float* bc        = (const float*)d_in[24];
    const int* rm_src      = (const int*)d_in[27];
    const int* rm_dst      = (const int*)d_in[28];
    float* out = (float*)d_out;

    char* w0p = (char*)d_ws;
    char* w = w0p;
    auto carve = [&](size_t bytes) -> void* {
        void* p = (void*)w;
        w += (bytes + 511) & ~(size_t)511;
        return p;
    };
    float* als    = (float*)carve((size_t)NST * 2 * 4);
    float* hsW    = (float*)carve((size_t)NST * 20 * 4);
    float* V      = (float*)carve((size_t)DFACT * 2 * 4);
    float* cst    = (float*)carve(64);
    int*   cursor = (int*)carve((size_t)(NFACT + 1) * 4);
    int*   perm   = (int*)carve((size_t)NFACT * MAXDEG * 4);   // 12.8 MB atomic-slot buckets
    if ((size_t)(w - w0p) > ws_size) {
        k_sentinel<<<(out_size + 255) / 256, 256, 0, stream>>>(out, out_size, 2000.f);
        return;
    }

    const int scat_blocks = (EM + 255) / 256;   // 1954

    // op1: zero bucket cursors (DMA, ~200 KB)
    (void)hipMemsetAsync(cursor, 0, (size_t)(NFACT + 1) * 4, stream);

    // op2: cst | V | statute hs (2000-way parallel) | atomic-slot scatter — one launch
    k_pre<<<PRE_SCAT0 + scat_blocks, 256, 0, stream>>>(x_statute, Wsrc_rm, asrc_rm, Wc,
                                                       Wdst_rm, adst_rm, b_rm, bc,
                                                       rm_src, rm_dst,
                                                       als, hsW, V, cst, cursor, perm);

    // op3: fused ald + softmax-weighted aggregation -> classifier output
    k_agg<<<NFACT / 4, 256, 0, stream>>>(x_fact, V, hsW, cursor, perm,
                                         (const float2*)als, cst, out);
}